// Round 13
// baseline (182.329 us; speedup 1.0000x reference)
//
#include <hip/hip_runtime.h>
#include <hip/hip_cooperative_groups.h>

namespace cg = cooperative_groups;

#define QUERY 16
#define LATENT 64

typedef float f4 __attribute__((ext_vector_type(4)));

// Workspace layout (floats):
//   Cxy  @ 0      : [16][32][32] = 16384
//   Cxz  @ 16384  : [16][32][16] =  8192
//   Cyz  @ 24576  : [16][32][16] =  8192
//   Ctx  @ 32768  : [16][ 8][32] =  4096
//   Cty  @ 36864  : [16][ 8][32] =  4096
//   Ctz  @ 40960  : [16][ 8][16] =  2048
//
// Measured: conv 3.5 us warm / ~4.5 cold; voxel 20.1 us warm / 21.9 cold at
// 83-85% HBM write peak (= harness fill ceiling). Residual ~11 us matches a
// per-dispatch overhead measured twice (R5: +12.7 us for an extra warm
// dispatch; R8 accounting: 11.5 us). This round fuses both phases into ONE
// cooperative kernel (512 blocks x 512 thr = 2/CU co-resident, 61.5 KB LDS)
// to remove the inter-dispatch boundary. Work per phase is unchanged.

// ---------------------------------------------------------------------------
// Conv phase (R11 v6 body): one block = (plane, oc, 128-px chunk). 8 waves:
// tid&127 = pixel, tid>>7 = ic-group (16 ic, wave-uniform). All 64 ic staged
// at once; weights via block-uniform s_loads; LDS reduce over 4 ic-groups.
// ---------------------------------------------------------------------------
template<int H, int Wd, int CH, int WSOFF>
__device__ __forceinline__ void conv_block(
    const float* __restrict__ in, const float* __restrict__ Wt,
    const float* __restrict__ bias, float* __restrict__ ws,
    float* __restrict__ smem, int plane, int oc, int chunk)
{
    constexpr int PW    = Wd + 8;
    constexpr int ROWS  = CH + 2;
    constexpr int SLAB  = ROWS * PW;         // 240 floats both shapes
    constexpr int HW    = H * Wd;
    constexpr int LOGW  = (Wd == 32) ? 5 : 4;
    constexpr int RF4   = Wd / 4;
    constexpr int RPI   = ROWS * RF4;
    constexpr int TOTF4 = LATENT * RPI;
    constexpr int NF4   = LATENT * SLAB / 4;

    const int tid = threadIdx.x;

    {
        const f4 zz = {0.f, 0.f, 0.f, 0.f};
        for (int i = tid; i < NF4; i += 512)
            reinterpret_cast<f4*>(smem)[i] = zz;
    }
    __syncthreads();

    #pragma unroll
    for (int s = tid; s < TOTF4; s += 512) {
        const int il  = s / RPI;
        const int rem = s - il * RPI;
        const int r2  = rem / RF4;
        const int c4  = rem - r2 * RF4;
        const int gr  = chunk * CH + r2 - 1;
        if ((unsigned)gr < (unsigned)H) {
            const f4 v = *reinterpret_cast<const f4*>(
                in + il * HW + gr * Wd + (c4 << 2));
            *reinterpret_cast<f4*>(
                smem + il * SLAB + r2 * PW + 4 + (c4 << 2)) = v;
        }
    }
    __syncthreads();

    const int px  = tid & 127;
    const int icg = __builtin_amdgcn_readfirstlane(tid >> 7);
    const int r   = px >> LOGW;
    const int c   = px & (Wd - 1);

    const float* __restrict__ w0 = Wt + (size_t)((plane * QUERY + oc) * LATENT) * 9;
    const float* base = smem + icg * 16 * SLAB + (r + 1) * PW + (c + 4);

    float a0 = 0.f, a1 = 0.f, a2 = 0.f;

    #pragma unroll 4
    for (int il = 0; il < 16; ++il) {
        const float* bp = base + il * SLAB;
        const float t0 = bp[-PW - 1], t1 = bp[-PW], t2 = bp[-PW + 1];
        const float t3 = bp[-1],      t4 = bp[0],   t5 = bp[1];
        const float t6 = bp[PW - 1],  t7 = bp[PW],  t8 = bp[PW + 1];
        const float* wa = w0 + (icg * 16 + il) * 9;
        a0 += t0 * wa[0] + t1 * wa[1] + t2 * wa[2];
        a1 += t3 * wa[3] + t4 * wa[4] + t5 * wa[5];
        a2 += t6 * wa[6] + t7 * wa[7] + t8 * wa[8];
    }

    float* red = smem + LATENT * SLAB;     // 384 floats
    const float pa = (a0 + a1) + a2;
    if (icg) red[((icg - 1) << 7) + px] = pa;
    __syncthreads();
    if (tid < 128) {
        const float sa = pa + red[px] + red[128 + px] + red[256 + px]
                       + bias[plane * QUERY + oc];
        ws[WSOFF + oc * HW + chunk * 128 + px] = fmaxf(sa, 0.0f);
    }
}

// ---------------------------------------------------------------------------
// Fused kernel: blocks 0..335 run conv (map as R11), then grid-wide sync,
// then ALL 512 blocks run the voxel phase (R8 body, measured at the write
// roofline) reusing the same LDS.
// ---------------------------------------------------------------------------
__global__ void __launch_bounds__(512)
fused_kernel(const float* __restrict__ p0, const float* __restrict__ p1,
             const float* __restrict__ p2, const float* __restrict__ p3,
             const float* __restrict__ p4, const float* __restrict__ p5,
             const float* __restrict__ Wt, const float* __restrict__ bias,
             float* __restrict__ ws, float* __restrict__ out)
{
    __shared__ float smem[15744];   // conv: 64*240 staging + 384 red = 61.5 KB
    const int blk = blockIdx.x;

    // ---- phase 1: conv (blocks 0..335; 336..511 idle to the sync) ----
    if (blk < 128) {
        const int l = blk;
        conv_block<32, 32, 4, 0>(p0, Wt, bias, ws, smem, 0, l >> 3, l & 7);
    } else if (blk < 192) {
        const int l = blk - 128;
        conv_block<32, 16, 8, 16384>(p1, Wt, bias, ws, smem, 1, l >> 2, l & 3);
    } else if (blk < 256) {
        const int l = blk - 192;
        conv_block<32, 16, 8, 24576>(p2, Wt, bias, ws, smem, 2, l >> 2, l & 3);
    } else if (blk < 288) {
        const int l = blk - 256;
        conv_block<8, 32, 4, 32768>(p3, Wt, bias, ws, smem, 3, l >> 1, l & 1);
    } else if (blk < 320) {
        const int l = blk - 288;
        conv_block<8, 32, 4, 36864>(p4, Wt, bias, ws, smem, 4, l >> 1, l & 1);
    } else if (blk < 336) {
        const int l = blk - 320;
        conv_block<8, 16, 8, 40960>(p5, Wt, bias, ws, smem, 5, l, 0);
    }

    __threadfence();                 // make ws visible device-wide
    cg::this_grid().sync();          // grid barrier (cooperative launch)

    // ---- phase 2: voxel (all 512 blocks) ----
    float* F  = smem;                // 4096: [y2l=16][z2=16][q=16]
    float* G  = smem + 4096;         // 256:  [y2l=16][q=16]
    float* Hh = smem + 4352;         // 256:  [z2=16][q=16]

    const int x2  = blk & 31;
    const int t2  = (blk >> 5) & 7;
    const int yh2 = blk >> 8;
    const int tid = threadIdx.x;

    const float* Cxy = ws;
    const float* Cxz = ws + 16384;
    const float* Cyz = ws + 24576;
    const float* Ctx = ws + 32768;
    const float* Cty = ws + 36864;
    const float* Ctz = ws + 40960;

    if (tid < 256) {
        const int y2l = tid >> 4, q = tid & 15;
        const int y2  = yh2 * 16 + y2l;
        G[tid] = Cxy[q * 1024 + x2 * 32 + y2] * Cty[q * 256 + t2 * 32 + y2];
    } else {
        const int i  = tid - 256;
        const int z2 = i >> 4, q = i & 15;
        Hh[i] = Cxz[q * 512 + x2 * 16 + z2]
              * Ctz[q * 128 + t2 * 16 + z2]
              * Ctx[q * 256 + t2 * 32 + x2];
    }
    __syncthreads();

    #pragma unroll
    for (int e = tid; e < 4096; e += 512) {
        const int q   = e & 15;
        const int z2  = (e >> 4) & 15;
        const int y2l = e >> 8;
        const int y2  = yh2 * 16 + y2l;
        F[e] = G[(y2l << 4) | q] * Hh[(z2 << 4) | q]
             * Cyz[q * 512 + (y2 << 4) + z2];
    }
    __syncthreads();

    const int j0  = (tid & 3) << 2;
    const int z   = (tid >> 2) & 31;
    const int yhp = (tid >> 7) & 1;   // y parity
    const int xl  = (tid >> 8) & 1;
    const int x   = (x2 << 1) | xl;
    const int t0_ = t2 << 1;
    const int y0  = yh2 * 32 + yhp;

    float* ob0 = out + ((((size_t)(t0_ * 64 + x)) * 64 + y0) * 32 + z) * 16 + j0;
    float* ob1 = ob0 + (size_t)64 * 64 * 32 * 16;   // t+1
    const float* Fb = F + ((z >> 1) << 4) + j0;

    #pragma unroll
    for (int y2l = 0; y2l < 16; ++y2l) {
        const f4 v = *reinterpret_cast<const f4*>(Fb + (y2l << 8));
        *reinterpret_cast<f4*>(ob0 + (size_t)y2l * 1024) = v;
        *reinterpret_cast<f4*>(ob1 + (size_t)y2l * 1024) = v;
    }
}

extern "C" void kernel_launch(void* const* d_in, const int* in_sizes, int n_in,
                              void* d_out, int out_size, void* d_ws, size_t ws_size,
                              hipStream_t stream)
{
    const float* p_xy = (const float*)d_in[0];
    const float* p_xz = (const float*)d_in[1];
    const float* p_yz = (const float*)d_in[2];
    const float* p_tx = (const float*)d_in[3];
    const float* p_ty = (const float*)d_in[4];
    const float* p_tz = (const float*)d_in[5];
    const float* Wt   = (const float*)d_in[6];
    const float* bias = (const float*)d_in[7];

    float* ws  = (float*)d_ws;
    float* out = (float*)d_out;

    void* args[] = {
        (void*)&p_xy, (void*)&p_xz, (void*)&p_yz,
        (void*)&p_tx, (void*)&p_ty, (void*)&p_tz,
        (void*)&Wt,   (void*)&bias, (void*)&ws, (void*)&out
    };
    hipLaunchCooperativeKernel((void*)fused_kernel, dim3(512), dim3(512),
                               args, 0, stream);
}

// Round 14
// 37.382 us; speedup vs baseline: 4.8775x; 4.8775x over previous
//
#include <hip/hip_runtime.h>

#define QUERY 16
#define LATENT 64

typedef float f4 __attribute__((ext_vector_type(4)));

// FINAL CONFIG (revert to R8, best measured: 37.41 us).
// Measured ledger:
//   conv:  3.5 us warm / ~4.5 us cold (repeat probes R7/R10)
//   voxel: 20.1 us warm / ~21.9 us cold at 83-85% of HBM write peak
//          (= harness fillBufferAligned's own ceiling; nt stores and
//           cooperative fusion both strictly worse: R9 +2.8us, R13 +145us)
//   ~11 us: fixed per-dispatch/replay overhead (measured twice: R5, R8),
//           insensitive to kernel structure (R11/R12/R13 all flat or worse).
//
// Workspace layout (floats):
//   Cxy  @ 0      : [16][32][32] = 16384
//   Cxz  @ 16384  : [16][32][16] =  8192
//   Cyz  @ 24576  : [16][32][16] =  8192
//   Ctx  @ 32768  : [16][ 8][32] =  4096
//   Cty  @ 36864  : [16][ 8][32] =  4096
//   Ctz  @ 40960  : [16][ 8][16] =  2048

// ---------------------------------------------------------------------------
// Conv v5: one block = (plane, oc-pair, 128-px chunk). 512 threads = 8 waves:
// tid&127 = pixel, tid>>7 = ic-group (16 ic, wave-uniform -> readfirstlane
// keeps weight loads scalar). All 64 ic staged at once (60 KB), single
// barrier pair, LDS reduction across 4 ic-groups.
// ---------------------------------------------------------------------------
template<int H, int Wd, int CH, int WSOFF>
__device__ __forceinline__ void conv_block(
    const float* __restrict__ in, const float* __restrict__ Wt,
    const float* __restrict__ bias, float* __restrict__ ws,
    float* __restrict__ smem, int plane, int oc0, int chunk)
{
    constexpr int PW    = Wd + 8;            // padded row: 16B-aligned interior
    constexpr int ROWS  = CH + 2;
    constexpr int SLAB  = ROWS * PW;         // 240 floats for both shapes
    constexpr int HW    = H * Wd;
    constexpr int LOGW  = (Wd == 32) ? 5 : 4;
    constexpr int RF4   = Wd / 4;            // f4 per interior row
    constexpr int RPI   = ROWS * RF4;        // f4 per ic
    constexpr int TOTF4 = LATENT * RPI;      // interior f4 to copy
    constexpr int NF4   = LATENT * SLAB / 4; // f4 in staging region

    const int tid = threadIdx.x;

    // zero fill staging region (halos stay zero)
    {
        const f4 zz = {0.f, 0.f, 0.f, 0.f};
        for (int i = tid; i < NF4; i += 512)
            reinterpret_cast<f4*>(smem)[i] = zz;
    }
    __syncthreads();

    // stage all 64 ic: coalesced f4 loads -> aligned ds_write_b128
    #pragma unroll
    for (int s = tid; s < TOTF4; s += 512) {
        const int il  = s / RPI;
        const int rem = s - il * RPI;
        const int r2  = rem / RF4;
        const int c4  = rem - r2 * RF4;
        const int gr  = chunk * CH + r2 - 1;
        if ((unsigned)gr < (unsigned)H) {
            const f4 v = *reinterpret_cast<const f4*>(
                in + il * HW + gr * Wd + (c4 << 2));
            *reinterpret_cast<f4*>(
                smem + il * SLAB + r2 * PW + 4 + (c4 << 2)) = v;
        }
    }
    __syncthreads();

    const int px  = tid & 127;
    const int icg = __builtin_amdgcn_readfirstlane(tid >> 7);  // 0..3, wave-uniform
    const int r   = px >> LOGW;
    const int c   = px & (Wd - 1);

    const float* __restrict__ w0 = Wt + (size_t)((plane * QUERY + oc0) * LATENT) * 9;
    const float* __restrict__ w1 = w0 + LATENT * 9;
    const float* base = smem + icg * 16 * SLAB + (r + 1) * PW + (c + 4);

    float a0 = 0.f, a1 = 0.f, a2 = 0.f;
    float b0 = 0.f, b1 = 0.f, b2 = 0.f;

    #pragma unroll 4
    for (int il = 0; il < 16; ++il) {
        const float* bp = base + il * SLAB;
        const float t0 = bp[-PW - 1], t1 = bp[-PW], t2 = bp[-PW + 1];
        const float t3 = bp[-1],      t4 = bp[0],   t5 = bp[1];
        const float t6 = bp[PW - 1],  t7 = bp[PW],  t8 = bp[PW + 1];
        const float* wa = w0 + (icg * 16 + il) * 9;
        const float* wb = w1 + (icg * 16 + il) * 9;
        a0 += t0 * wa[0] + t1 * wa[1] + t2 * wa[2];
        a1 += t3 * wa[3] + t4 * wa[4] + t5 * wa[5];
        a2 += t6 * wa[6] + t7 * wa[7] + t8 * wa[8];
        b0 += t0 * wb[0] + t1 * wb[1] + t2 * wb[2];
        b1 += t3 * wb[3] + t4 * wb[4] + t5 * wb[5];
        b2 += t6 * wb[6] + t7 * wb[7] + t8 * wb[8];
    }

    // cross-ic-group reduction: groups 1..3 park partials in LDS tail
    float* red = smem + LATENT * SLAB;     // 768 floats
    const float pa = (a0 + a1) + a2;
    const float pb = (b0 + b1) + b2;
    if (icg) {
        red[((icg - 1) << 8) + (px << 1)    ] = pa;
        red[((icg - 1) << 8) + (px << 1) + 1] = pb;
    }
    __syncthreads();
    if (tid < 128) {
        const int e = px << 1;
        const float sa = pa + red[e]     + red[256 + e]     + red[512 + e]
                       + bias[plane * QUERY + oc0];
        const float sb = pb + red[e + 1] + red[256 + e + 1] + red[512 + e + 1]
                       + bias[plane * QUERY + oc0 + 1];
        ws[WSOFF + (oc0    ) * HW + chunk * 128 + px] = fmaxf(sa, 0.0f);
        ws[WSOFF + (oc0 + 1) * HW + chunk * 128 + px] = fmaxf(sb, 0.0f);
    }
}

// Block map (168 blocks, 128 px each):
//  [  0, 64): xy  H=32 W=32 CH=4   (oc0 = (l>>3)*2, chunk = l&7)
//  [ 64, 96): xz  H=32 W=16 CH=8   (oc0 = (l>>2)*2, chunk = l&3)
//  [ 96,128): yz  H=32 W=16 CH=8
//  [128,144): tx  H= 8 W=32 CH=4   (oc0 = (l>>1)*2, chunk = l&1)
//  [144,160): ty  H= 8 W=32 CH=4
//  [160,168): tz  H= 8 W=16 CH=8   (oc0 = l*2, chunk = 0)
__global__ __launch_bounds__(512) void conv_relu_kernel(
    const float* __restrict__ p0, const float* __restrict__ p1,
    const float* __restrict__ p2, const float* __restrict__ p3,
    const float* __restrict__ p4, const float* __restrict__ p5,
    const float* __restrict__ Wt, const float* __restrict__ bias,
    float* __restrict__ ws)
{
    __shared__ float smem[16128];   // 64*240 staging + 768 reduction = 63 KB
    const int blk = blockIdx.x;

    if (blk < 64) {
        const int l = blk;
        conv_block<32, 32, 4, 0>(p0, Wt, bias, ws, smem, 0, (l >> 3) << 1, l & 7);
    } else if (blk < 96) {
        const int l = blk - 64;
        conv_block<32, 16, 8, 16384>(p1, Wt, bias, ws, smem, 1, (l >> 2) << 1, l & 3);
    } else if (blk < 128) {
        const int l = blk - 96;
        conv_block<32, 16, 8, 24576>(p2, Wt, bias, ws, smem, 2, (l >> 2) << 1, l & 3);
    } else if (blk < 144) {
        const int l = blk - 128;
        conv_block<8, 32, 4, 32768>(p3, Wt, bias, ws, smem, 3, (l >> 1) << 1, l & 1);
    } else if (blk < 160) {
        const int l = blk - 144;
        conv_block<8, 32, 4, 36864>(p4, Wt, bias, ws, smem, 4, (l >> 1) << 1, l & 1);
    } else {
        const int l = blk - 160;
        conv_block<8, 16, 8, 40960>(p5, Wt, bias, ws, smem, 5, l << 1, 0);
    }
}

// ---------------------------------------------------------------------------
// Voxel (measured at the write roofline: 20.1 us warm, 83-85% HBM peak,
// zero RFO/over-fetch; plain cached stores, which beat nt by 2.8 us).
// One block per (x2, t2, y2-half) -> 512 blocks. F built once; write loop:
// 1 ds_read_b128 feeds 2 dwordx4 stores (t = 2*t2, 2*t2+1).
// out flat: (((t*64 + x)*64 + y)*32 + z)*16 + q
// ---------------------------------------------------------------------------
__global__ __launch_bounds__(512) void voxel_kernel(
    const float* __restrict__ ws, float* __restrict__ out)
{
    __shared__ float F[4096];   // [y2l=16][z2=16][q=16]
    __shared__ float G[256];    // [y2l=16][q=16]  Cxy*Cty
    __shared__ float Hh[256];   // [z2=16][q=16]   Cxz*Ctz*Ctx

    const int b   = blockIdx.x;     // 0..511
    const int x2  = b & 31;
    const int t2  = (b >> 5) & 7;
    const int yh2 = b >> 8;         // y2 half: 0/1
    const int tid = threadIdx.x;    // 0..511

    const float* Cxy = ws;
    const float* Cxz = ws + 16384;
    const float* Cyz = ws + 24576;
    const float* Ctx = ws + 32768;
    const float* Cty = ws + 36864;
    const float* Ctz = ws + 40960;

    if (tid < 256) {
        const int y2l = tid >> 4, q = tid & 15;
        const int y2  = yh2 * 16 + y2l;
        G[tid] = Cxy[q * 1024 + x2 * 32 + y2] * Cty[q * 256 + t2 * 32 + y2];
    } else {
        const int i  = tid - 256;
        const int z2 = i >> 4, q = i & 15;
        Hh[i] = Cxz[q * 512 + x2 * 16 + z2]
              * Ctz[q * 128 + t2 * 16 + z2]
              * Ctx[q * 256 + t2 * 32 + x2];
    }
    __syncthreads();

    #pragma unroll
    for (int e = tid; e < 4096; e += 512) {
        const int q   = e & 15;
        const int z2  = (e >> 4) & 15;
        const int y2l = e >> 8;
        const int y2  = yh2 * 16 + y2l;
        F[e] = G[(y2l << 4) | q] * Hh[(z2 << 4) | q]
             * Cyz[q * 512 + (y2 << 4) + z2];
    }
    __syncthreads();

    const int j0  = (tid & 3) << 2;
    const int z   = (tid >> 2) & 31;
    const int yhp = (tid >> 7) & 1;   // y parity
    const int xl  = (tid >> 8) & 1;
    const int x   = (x2 << 1) | xl;
    const int t0_ = t2 << 1;
    const int y0  = yh2 * 32 + yhp;

    float* ob0 = out + ((((size_t)(t0_ * 64 + x)) * 64 + y0) * 32 + z) * 16 + j0;
    float* ob1 = ob0 + (size_t)64 * 64 * 32 * 16;   // t+1
    const float* Fb = F + ((z >> 1) << 4) + j0;

    #pragma unroll
    for (int y2l = 0; y2l < 16; ++y2l) {
        const f4 v = *reinterpret_cast<const f4*>(Fb + (y2l << 8));
        *reinterpret_cast<f4*>(ob0 + (size_t)y2l * 1024) = v;
        *reinterpret_cast<f4*>(ob1 + (size_t)y2l * 1024) = v;
    }
}

extern "C" void kernel_launch(void* const* d_in, const int* in_sizes, int n_in,
                              void* d_out, int out_size, void* d_ws, size_t ws_size,
                              hipStream_t stream)
{
    const float* p_xy = (const float*)d_in[0];
    const float* p_xz = (const float*)d_in[1];
    const float* p_yz = (const float*)d_in[2];
    const float* p_tx = (const float*)d_in[3];
    const float* p_ty = (const float*)d_in[4];
    const float* p_tz = (const float*)d_in[5];
    const float* Wt   = (const float*)d_in[6];
    const float* bias = (const float*)d_in[7];

    float* ws  = (float*)d_ws;
    float* out = (float*)d_out;

    conv_relu_kernel<<<168, 512, 0, stream>>>(p_xy, p_xz, p_yz, p_tx, p_ty, p_tz,
                                              Wt, bias, ws);
    voxel_kernel<<<512, 512, 0, stream>>>(ws, out);
}